// Round 19
// baseline (448.394 us; speedup 1.0000x reference)
//
#include <hip/hip_runtime.h>

#define N_USERS 100000
#define N_ITEMS 50000
#define N_NODES 150000
#define EMBED 64
#define N_LAYERS 3

#define BSH 7                                   // log2(rows per bucket)
#define BROWS 128                               // rows per bucket
#define NB ((N_NODES + BROWS - 1) / BROWS)      // 1172 buckets
#define PCHUNK 4096                             // edges per partition WG
#define COLMASK 0x3FFFF                         // 18 bits for col (N_NODES<2^18)
#define CAPB 4608                               // bsort staging capacity (mean 4096 + 8 sigma)
#define CSH 14                                  // col-range shift: 16384 nodes = 2 MB of x
#define KK (BROWS << 4)                         // 2048 sort keys (row x col-range)

// float -> bf16 (round-to-nearest-even), bf16 -> float
__device__ __forceinline__ unsigned short f2bf(float f) {
    unsigned u = __float_as_uint(f);
    return (unsigned short)((u + 0x7FFFu + ((u >> 16) & 1u)) >> 16);
}
__device__ __forceinline__ float bf2f(unsigned short h) {
    return __uint_as_float(((unsigned)h) << 16);
}

// ---------------------------------------------------------------------------
// init: ego0(bf16) = concat(u+u_pre, i+i_pre)  (acc deferred to final layer)
// ---------------------------------------------------------------------------
__global__ void lgcn_init(const float* __restrict__ u, const float* __restrict__ it,
                          const float* __restrict__ up, const float* __restrict__ ip,
                          unsigned short* __restrict__ egoh) {
    int idx = blockIdx.x * blockDim.x + threadIdx.x;  // float4 index
    const int total = N_NODES * EMBED / 4;
    if (idx >= total) return;
    const int uCount = N_USERS * EMBED / 4;
    float4 v;
    if (idx < uCount) {
        float4 a = reinterpret_cast<const float4*>(u)[idx];
        float4 b = reinterpret_cast<const float4*>(up)[idx];
        v = make_float4(a.x + b.x, a.y + b.y, a.z + b.z, a.w + b.w);
    } else {
        int j = idx - uCount;
        float4 a = reinterpret_cast<const float4*>(it)[j];
        float4 b = reinterpret_cast<const float4*>(ip)[j];
        v = make_float4(a.x + b.x, a.y + b.y, a.z + b.z, a.w + b.w);
    }
    ushort4 h;
    h.x = f2bf(v.x); h.y = f2bf(v.y); h.z = f2bf(v.z); h.w = f2bf(v.w);
    reinterpret_cast<ushort4*>(egoh)[idx] = h;
}

// ---------------------------------------------------------------------------
// pass A: per-WG bucket histogram -> Cmat[wg][b]  (no global atomics)
// ---------------------------------------------------------------------------
__global__ void lgcn_cnt(const int* __restrict__ rows, int* __restrict__ Cmat, int nnz) {
    __shared__ int lcnt[NB];
    int wg = blockIdx.x;
    int c0 = wg * PCHUNK;
    int cend = min(c0 + PCHUNK, nnz);
    for (int b = threadIdx.x; b < NB; b += blockDim.x) lcnt[b] = 0;
    __syncthreads();
    for (int e = c0 + threadIdx.x; e < cend; e += blockDim.x)
        atomicAdd(&lcnt[rows[e] >> BSH], 1);
    __syncthreads();
    for (int b = threadIdx.x; b < NB; b += blockDim.x)
        Cmat[(size_t)wg * NB + b] = lcnt[b];
}

// ---------------------------------------------------------------------------
// colscan: one block per bucket b; exclusive scan of Cmat[:,b] over nwg WGs
// (in-place) + column total.
// ---------------------------------------------------------------------------
__global__ __launch_bounds__(256) void lgcn_colscan(int* __restrict__ Cmat,
                                                    int* __restrict__ colTotal, int nwg) {
    __shared__ int sm[256];
    int b = blockIdx.x;
    int carry = 0;
    for (int c0 = 0; c0 < nwg; c0 += 256) {
        int wg = c0 + threadIdx.x;
        int v = (wg < nwg) ? Cmat[(size_t)wg * NB + b] : 0;
        sm[threadIdx.x] = v;
        __syncthreads();
        for (int off = 1; off < 256; off <<= 1) {
            int t = (threadIdx.x >= (unsigned)off) ? sm[threadIdx.x - off] : 0;
            __syncthreads();
            sm[threadIdx.x] += t;
            __syncthreads();
        }
        if (wg < nwg) Cmat[(size_t)wg * NB + b] = carry + sm[threadIdx.x] - v;
        carry += sm[255];
        __syncthreads();
    }
    if (threadIdx.x == 0) colTotal[b] = carry;
}

// ---------------------------------------------------------------------------
// btscan: exclusive scan of colTotal[NB] -> bucketBase[NB+1]; looped chunks
// of 1024 (NB=1172 > 1024); sentinels.
// ---------------------------------------------------------------------------
__global__ __launch_bounds__(1024) void lgcn_btscan(const int* __restrict__ colTotal,
                                                    int* __restrict__ bucketBase,
                                                    int* __restrict__ rowptr, int nnz) {
    __shared__ int sm[1024];
    __shared__ int carry_s;
    if (threadIdx.x == 0) carry_s = 0;
    __syncthreads();
    for (int base = 0; base < NB; base += 1024) {
        int i = base + threadIdx.x;
        int c = (i < NB) ? colTotal[i] : 0;
        sm[threadIdx.x] = c;
        __syncthreads();
        for (int off = 1; off < 1024; off <<= 1) {
            int t = (threadIdx.x >= (unsigned)off) ? sm[threadIdx.x - off] : 0;
            __syncthreads();
            sm[threadIdx.x] += t;
            __syncthreads();
        }
        int r0 = carry_s;
        if (i < NB) bucketBase[i] = r0 + sm[threadIdx.x] - c;
        int tot = sm[1023];
        __syncthreads();
        if (threadIdx.x == 0) carry_s = r0 + tot;
        __syncthreads();
    }
    if (threadIdx.x == 0) { bucketBase[NB] = nnz; rowptr[N_NODES] = nnz; }
}

// ---------------------------------------------------------------------------
// pass B: LDS-staged scatter. Locally bucket-sort the WG's 4096 edges in LDS,
// then stream them out in global-position order -> coalesced writes, zero
// global atomics. int2{ (rowLocal<<18)|col , bits(val) }.
// ---------------------------------------------------------------------------
__global__ __launch_bounds__(256) void lgcn_scatter(
        const int* __restrict__ rows, const int* __restrict__ cols,
        const float* __restrict__ vals, const int* __restrict__ Cmat,
        const int* __restrict__ bucketBase, int2* __restrict__ pcvp, int nnz) {
    __shared__ int lcnt[NB];                 // hist -> local cursor
    __shared__ int gbase[NB];                // global base - local offset
    __shared__ int sc[256];                  // scan temp
    __shared__ int2 ebuf[PCHUNK];            // 32 KB staging
    __shared__ unsigned short bbuf[PCHUNK];  // 8 KB bucket ids
    int wg = blockIdx.x;
    int c0 = wg * PCHUNK;
    int cend = min(c0 + PCHUNK, nnz);
    int n = cend - c0;

    for (int b = threadIdx.x; b < NB; b += 256) lcnt[b] = 0;
    __syncthreads();
    for (int e = c0 + threadIdx.x; e < cend; e += 256)
        atomicAdd(&lcnt[rows[e] >> BSH], 1);
    __syncthreads();

    // exclusive scan of lcnt[0..NB) with 256-thread chunks + carry
    int carry = 0;
    for (int base = 0; base < NB; base += 256) {
        int b = base + threadIdx.x;
        int v = (b < NB) ? lcnt[b] : 0;
        sc[threadIdx.x] = v;
        __syncthreads();
        for (int off = 1; off < 256; off <<= 1) {
            int t = (threadIdx.x >= (unsigned)off) ? sc[threadIdx.x - off] : 0;
            __syncthreads();
            sc[threadIdx.x] += t;
            __syncthreads();
        }
        if (b < NB) {
            int excl = carry + sc[threadIdx.x] - v;
            gbase[b] = bucketBase[b] + Cmat[(size_t)wg * NB + b] - excl;
            lcnt[b] = excl;   // becomes the local cursor
        }
        carry += sc[255];
        __syncthreads();
    }

    // local bucket-sort into LDS
    for (int e = c0 + threadIdx.x; e < cend; e += 256) {
        int r = rows[e];
        int b = r >> BSH;
        int lpos = atomicAdd(&lcnt[b], 1);
        ebuf[lpos] = make_int2(((r & (BROWS - 1)) << 18) | cols[e], __float_as_int(vals[e]));
        bbuf[lpos] = (unsigned short)b;
    }
    __syncthreads();

    // stream out: consecutive t -> consecutive global positions within runs
    for (int t = threadIdx.x; t < n; t += 256) {
        int b = bbuf[t];
        pcvp[gbase[b] + t] = ebuf[t];
    }
}

// ---------------------------------------------------------------------------
// bsort: one WG (256 thr) per 128-row bucket. Sort key = (rowLocal<<4) |
// (col>>CSH): row-major, then 16 column-ranges of 2 MB of x each -> spmm
// walks each row's edges in ascending column-range order (L2-friendly).
// Row segments stay contiguous; rowptr[node] = scan value at key rl<<4.
// cv.x stores col<<6 (pre-shifted). LDS staging -> coalesced stream-out.
// ---------------------------------------------------------------------------
__global__ __launch_bounds__(256) void lgcn_bsort(const int2* __restrict__ pcvp,
                                                  const int* __restrict__ bucketBase,
                                                  int* __restrict__ rowptr,
                                                  int2* __restrict__ cv) {
    __shared__ int sm[KK];                   // 8 KB hist
    __shared__ int cur[KK];                  // 8 KB cursors
    __shared__ int sc[256];                  // scan temp
    __shared__ int2 sbuf[CAPB];              // 36 KB staging
    int b = blockIdx.x;
    int beg = bucketBase[b];
    int end = bucketBase[b + 1];
    int n = end - beg;

    for (int k = threadIdx.x; k < KK; k += 256) sm[k] = 0;
    __syncthreads();
    for (int i = beg + threadIdx.x; i < end; i += 256) {
        int px = pcvp[i].x;
        int key = ((((unsigned)px) >> 18) << 4) | (((unsigned)(px & COLMASK)) >> CSH);
        atomicAdd(&sm[key], 1);
    }
    __syncthreads();

    // exclusive scan of sm[0..KK) -> cur (KK multiple of 256)
    int carry = 0;
    for (int base = 0; base < KK; base += 256) {
        int k = base + threadIdx.x;
        int v = sm[k];
        sc[threadIdx.x] = v;
        __syncthreads();
        for (int off = 1; off < 256; off <<= 1) {
            int t = (threadIdx.x >= (unsigned)off) ? sc[threadIdx.x - off] : 0;
            __syncthreads();
            sc[threadIdx.x] += t;
            __syncthreads();
        }
        cur[k] = carry + sc[threadIdx.x] - v;
        carry += sc[255];
        __syncthreads();
    }

    // rowptr at key boundaries (rl<<4 = first col-range of row rl)
    if (threadIdx.x < BROWS) {
        int node = b * BROWS + (int)threadIdx.x;
        if (node < N_NODES) rowptr[node] = beg + cur[threadIdx.x << 4];
    }
    __syncthreads();

    if (n <= CAPB) {
        // staged: sort into LDS, stream out coalesced
        for (int i = beg + threadIdx.x; i < end; i += 256) {
            int2 p = pcvp[i];
            int key = ((((unsigned)p.x) >> 18) << 4) | (((unsigned)(p.x & COLMASK)) >> CSH);
            int lpos = atomicAdd(&cur[key], 1);
            sbuf[lpos] = make_int2((p.x & COLMASK) << 6, p.y);
        }
        __syncthreads();
        for (int t = threadIdx.x; t < n; t += 256)
            cv[beg + t] = sbuf[t];
    } else {
        // fallback: direct exact-position writes (memory-safe path)
        for (int i = beg + threadIdx.x; i < end; i += 256) {
            int2 p = pcvp[i];
            int key = ((((unsigned)p.x) >> 18) << 4) | (((unsigned)(p.x & COLMASK)) >> CSH);
            int pos = atomicAdd(&cur[key], 1);
            cv[beg + pos] = make_int2((p.x & COLMASK) << 6, p.y);
        }
    }
}

// ---------------------------------------------------------------------------
// CSR SpMM quad: one wave per row; 4 edges per wave-instruction; depth-2
// ping-pong. Main loop is UNPREDICATED (runs while e+8 <= end: all indices
// provably in range); one predicated iteration + epilogue handle the tail.
// cv.x holds col<<6 (pre-shifted).
// FINAL=false: write bf16 ego only. FINAL=true: acc = (e0+e1+e2+s)*scale.
// ---------------------------------------------------------------------------
#define CONSUME(vv, qq)                                              \
    s.x = fmaf(vv, __uint_as_float(qq.x << 16), s.x);                \
    s.y = fmaf(vv, __uint_as_float(qq.x & 0xFFFF0000u), s.y);        \
    s.z = fmaf(vv, __uint_as_float(qq.y << 16), s.z);                \
    s.w = fmaf(vv, __uint_as_float(qq.y & 0xFFFF0000u), s.w);

template <bool FINAL>
__global__ __launch_bounds__(256) void lgcn_spmm_quad(
        const int* __restrict__ rowptr, const int2* __restrict__ cv,
        const unsigned short* __restrict__ x, unsigned short* __restrict__ ego_out,
        const unsigned short* __restrict__ e0, const unsigned short* __restrict__ e1,
        const unsigned short* __restrict__ e2, float* __restrict__ acc, float scale) {
    int row = blockIdx.x * 4 + (threadIdx.x >> 6);
    row = __builtin_amdgcn_readfirstlane(row);   // wave-uniform
    if (row >= N_NODES) return;
    int lane = threadIdx.x & 63;
    int grp  = lane >> 4;
    int sub  = lane & 15;
    int beg = rowptr[row];
    int end = rowptr[row + 1];

    // hoisted epilogue streams (lanes 0-15 only) — overlap the gather loop
    ushort4 h0, h1, h2;
    if (FINAL && grp == 0) {
        size_t o4 = (size_t)row * 16 + sub;
        h0 = reinterpret_cast<const ushort4*>(e0)[o4];
        h1 = reinterpret_cast<const ushort4*>(e1)[o4];
        h2 = reinterpret_cast<const ushort4*>(e2)[o4];
    }

    float4 s = make_float4(0.f, 0.f, 0.f, 0.f);
    if (beg < end) {
        int lim = end - 1;
        int eg = grp;
        int so = sub << 2;
        // clamped prologue: A@beg, B@beg+4
        int   iA = min(beg + eg, lim);
        int2  pA = cv[iA];
        float vA = (beg + eg <= lim) ? __int_as_float(pA.y) : 0.f;
        uint2 qA = *reinterpret_cast<const uint2*>(x + (unsigned)pA.x + so);
        int   iB = min(beg + 4 + eg, lim);
        int2  pB = cv[iB];
        float vB = (beg + 4 + eg <= lim) ? __int_as_float(pB.y) : 0.f;
        uint2 qB = *reinterpret_cast<const uint2*>(x + (unsigned)pB.x + so);

        int e = beg + 8;
        // unpredicated bulk: all refill indices < end
        for (; e + 8 <= end; e += 8) {
            CONSUME(vA, qA)
            pA = cv[e + eg];
            vA = __int_as_float(pA.y);
            qA = *reinterpret_cast<const uint2*>(x + (unsigned)pA.x + so);
            CONSUME(vB, qB)
            pB = cv[e + 4 + eg];
            vB = __int_as_float(pB.y);
            qB = *reinterpret_cast<const uint2*>(x + (unsigned)pB.x + so);
        }
        // one predicated (clamped) iteration for the tail
        if (e < end) {
            CONSUME(vA, qA)
            iA = min(e + eg, lim);
            pA = cv[iA];
            vA = (e + eg <= lim) ? __int_as_float(pA.y) : 0.f;
            qA = *reinterpret_cast<const uint2*>(x + (unsigned)pA.x + so);
            CONSUME(vB, qB)
            iB = min(e + 4 + eg, lim);
            pB = cv[iB];
            vB = (e + 4 + eg <= lim) ? __int_as_float(pB.y) : 0.f;
            qB = *reinterpret_cast<const uint2*>(x + (unsigned)pB.x + so);
        }
        CONSUME(vA, qA)
        CONSUME(vB, qB)
    }

    // combine the 4 edge-groups: lanes with same sub
    s.x += __shfl_xor(s.x, 16); s.x += __shfl_xor(s.x, 32);
    s.y += __shfl_xor(s.y, 16); s.y += __shfl_xor(s.y, 32);
    s.z += __shfl_xor(s.z, 16); s.z += __shfl_xor(s.z, 32);
    s.w += __shfl_xor(s.w, 16); s.w += __shfl_xor(s.w, 32);

    if (grp == 0) {
        size_t o4 = (size_t)row * 16 + sub;
        if (!FINAL) {
            ushort4 h;
            h.x = f2bf(s.x); h.y = f2bf(s.y); h.z = f2bf(s.z); h.w = f2bf(s.w);
            reinterpret_cast<ushort4*>(ego_out)[o4] = h;
        } else {
            float4 r;
            r.x = (bf2f(h0.x) + bf2f(h1.x) + bf2f(h2.x) + s.x) * scale;
            r.y = (bf2f(h0.y) + bf2f(h1.y) + bf2f(h2.y) + s.y) * scale;
            r.z = (bf2f(h0.z) + bf2f(h1.z) + bf2f(h2.z) + s.z) * scale;
            r.w = (bf2f(h0.w) + bf2f(h1.w) + bf2f(h2.w) + s.w) * scale;
            reinterpret_cast<float4*>(acc)[o4] = r;
        }
    }
}

extern "C" void kernel_launch(void* const* d_in, const int* in_sizes, int n_in,
                              void* d_out, int out_size, void* d_ws, size_t ws_size,
                              hipStream_t stream) {
    const int*   rows = (const int*)d_in[0];
    const int*   cols = (const int*)d_in[1];
    const float* vals = (const float*)d_in[2];
    const float* u    = (const float*)d_in[3];
    const float* it   = (const float*)d_in[4];
    const float* up   = (const float*)d_in[5];
    const float* ip   = (const float*)d_in[6];
    const int nnz = in_sizes[0];
    const int nwg = (nnz + PCHUNK - 1) / PCHUNK;

    float* acc = (float*)d_out;

    // workspace layout (~141 MB)
    unsigned short* egoh0 = (unsigned short*)d_ws;                    // 19.2 MB
    unsigned short* egoh1 = egoh0 + (size_t)N_NODES * EMBED;          // 19.2 MB
    unsigned short* egoh2 = egoh1 + (size_t)N_NODES * EMBED;          // 19.2 MB
    int2*  cv         = (int2*)(egoh2 + (size_t)N_NODES * EMBED);     // nnz*8 = 38.4 MB
    int2*  pcvp       = cv + nnz;                                     // nnz*8 = 38.4 MB
    int*   Cmat       = (int*)(pcvp + nnz);                           // nwg*NB ints (~5.5 MB)
    int*   colTotal   = Cmat + (size_t)nwg * NB;                      // NB
    int*   bucketBase = colTotal + NB;                                // NB+1
    int*   rowptr     = bucketBase + NB + 1;                          // N_NODES+1

    const int tpb = 256;
    const int totalVec = N_NODES * EMBED / 4;

    lgcn_init<<<(totalVec + tpb - 1) / tpb, tpb, 0, stream>>>(u, it, up, ip, egoh0);
    lgcn_cnt<<<nwg, tpb, 0, stream>>>(rows, Cmat, nnz);
    lgcn_colscan<<<NB, 256, 0, stream>>>(Cmat, colTotal, nwg);
    lgcn_btscan<<<1, 1024, 0, stream>>>(colTotal, bucketBase, rowptr, nnz);
    lgcn_scatter<<<nwg, tpb, 0, stream>>>(rows, cols, vals, Cmat, bucketBase, pcvp, nnz);
    lgcn_bsort<<<NB, 256, 0, stream>>>(pcvp, bucketBase, rowptr, cv);

    const int spmmBlocks = (N_NODES + 3) / 4;  // 4 rows (waves) per block

    lgcn_spmm_quad<false><<<spmmBlocks, tpb, 0, stream>>>(
        rowptr, cv, egoh0, egoh1, nullptr, nullptr, nullptr, nullptr, 1.0f);
    lgcn_spmm_quad<false><<<spmmBlocks, tpb, 0, stream>>>(
        rowptr, cv, egoh1, egoh2, nullptr, nullptr, nullptr, nullptr, 1.0f);
    lgcn_spmm_quad<true><<<spmmBlocks, tpb, 0, stream>>>(
        rowptr, cv, egoh2, nullptr, egoh0, egoh1, egoh2, acc, 1.0f / (N_LAYERS + 1));
}

// Round 20
// 409.888 us; speedup vs baseline: 1.0939x; 1.0939x over previous
//
#include <hip/hip_runtime.h>

#define N_USERS 100000
#define N_ITEMS 50000
#define N_NODES 150000
#define EMBED 64
#define N_LAYERS 3

#define BSH 7                                   // log2(rows per bucket)
#define BROWS 128                               // rows per bucket
#define NB ((N_NODES + BROWS - 1) / BROWS)      // 1172 buckets
#define PCHUNK 4096                             // edges per partition WG
#define COLMASK 0x3FFFF                         // 18 bits for col (N_NODES<2^18)
#define CAPB 4608                               // bsort staging capacity (mean 4096 + 8 sigma)

// float -> bf16 (round-to-nearest-even), bf16 halves of a packed u32
__device__ __forceinline__ unsigned short f2bf(float f) {
    unsigned u = __float_as_uint(f);
    return (unsigned short)((u + 0x7FFFu + ((u >> 16) & 1u)) >> 16);
}
__device__ __forceinline__ float blo(unsigned u) { return __uint_as_float(u << 16); }
__device__ __forceinline__ float bhi(unsigned u) { return __uint_as_float(u & 0xFFFF0000u); }

// ---------------------------------------------------------------------------
// init: ego0(bf16) = concat(u+u_pre, i+i_pre)  (acc deferred to final layer)
// ---------------------------------------------------------------------------
__global__ void lgcn_init(const float* __restrict__ u, const float* __restrict__ it,
                          const float* __restrict__ up, const float* __restrict__ ip,
                          unsigned short* __restrict__ egoh) {
    int idx = blockIdx.x * blockDim.x + threadIdx.x;  // float4 index
    const int total = N_NODES * EMBED / 4;
    if (idx >= total) return;
    const int uCount = N_USERS * EMBED / 4;
    float4 v;
    if (idx < uCount) {
        float4 a = reinterpret_cast<const float4*>(u)[idx];
        float4 b = reinterpret_cast<const float4*>(up)[idx];
        v = make_float4(a.x + b.x, a.y + b.y, a.z + b.z, a.w + b.w);
    } else {
        int j = idx - uCount;
        float4 a = reinterpret_cast<const float4*>(it)[j];
        float4 b = reinterpret_cast<const float4*>(ip)[j];
        v = make_float4(a.x + b.x, a.y + b.y, a.z + b.z, a.w + b.w);
    }
    ushort4 h;
    h.x = f2bf(v.x); h.y = f2bf(v.y); h.z = f2bf(v.z); h.w = f2bf(v.w);
    reinterpret_cast<ushort4*>(egoh)[idx] = h;
}

// ---------------------------------------------------------------------------
// pass A: per-WG bucket histogram -> Cmat[wg][b]  (no global atomics)
// ---------------------------------------------------------------------------
__global__ void lgcn_cnt(const int* __restrict__ rows, int* __restrict__ Cmat, int nnz) {
    __shared__ int lcnt[NB];
    int wg = blockIdx.x;
    int c0 = wg * PCHUNK;
    int cend = min(c0 + PCHUNK, nnz);
    for (int b = threadIdx.x; b < NB; b += blockDim.x) lcnt[b] = 0;
    __syncthreads();
    for (int e = c0 + threadIdx.x; e < cend; e += blockDim.x)
        atomicAdd(&lcnt[rows[e] >> BSH], 1);
    __syncthreads();
    for (int b = threadIdx.x; b < NB; b += blockDim.x)
        Cmat[(size_t)wg * NB + b] = lcnt[b];
}

// ---------------------------------------------------------------------------
// colscan: one block per bucket b; exclusive scan of Cmat[:,b] over nwg WGs
// (in-place) + column total.
// ---------------------------------------------------------------------------
__global__ __launch_bounds__(256) void lgcn_colscan(int* __restrict__ Cmat,
                                                    int* __restrict__ colTotal, int nwg) {
    __shared__ int sm[256];
    int b = blockIdx.x;
    int carry = 0;
    for (int c0 = 0; c0 < nwg; c0 += 256) {
        int wg = c0 + threadIdx.x;
        int v = (wg < nwg) ? Cmat[(size_t)wg * NB + b] : 0;
        sm[threadIdx.x] = v;
        __syncthreads();
        for (int off = 1; off < 256; off <<= 1) {
            int t = (threadIdx.x >= (unsigned)off) ? sm[threadIdx.x - off] : 0;
            __syncthreads();
            sm[threadIdx.x] += t;
            __syncthreads();
        }
        if (wg < nwg) Cmat[(size_t)wg * NB + b] = carry + sm[threadIdx.x] - v;
        carry += sm[255];
        __syncthreads();
    }
    if (threadIdx.x == 0) colTotal[b] = carry;
}

// ---------------------------------------------------------------------------
// btscan: exclusive scan of colTotal[NB] -> bucketBase[NB+1]; looped chunks
// of 1024 (NB=1172 > 1024); sentinels.
// ---------------------------------------------------------------------------
__global__ __launch_bounds__(1024) void lgcn_btscan(const int* __restrict__ colTotal,
                                                    int* __restrict__ bucketBase,
                                                    int* __restrict__ rowptr, int nnz) {
    __shared__ int sm[1024];
    __shared__ int carry_s;
    if (threadIdx.x == 0) carry_s = 0;
    __syncthreads();
    for (int base = 0; base < NB; base += 1024) {
        int i = base + threadIdx.x;
        int c = (i < NB) ? colTotal[i] : 0;
        sm[threadIdx.x] = c;
        __syncthreads();
        for (int off = 1; off < 1024; off <<= 1) {
            int t = (threadIdx.x >= (unsigned)off) ? sm[threadIdx.x - off] : 0;
            __syncthreads();
            sm[threadIdx.x] += t;
            __syncthreads();
        }
        int r0 = carry_s;
        if (i < NB) bucketBase[i] = r0 + sm[threadIdx.x] - c;
        int tot = sm[1023];
        __syncthreads();
        if (threadIdx.x == 0) carry_s = r0 + tot;
        __syncthreads();
    }
    if (threadIdx.x == 0) { bucketBase[NB] = nnz; rowptr[N_NODES] = nnz; }
}

// ---------------------------------------------------------------------------
// pass B: LDS-staged scatter. Locally bucket-sort the WG's 4096 edges in LDS,
// then stream them out in global-position order -> coalesced writes, zero
// global atomics. int2{ (rowLocal<<18)|col , bits(val) }.
// ---------------------------------------------------------------------------
__global__ __launch_bounds__(256) void lgcn_scatter(
        const int* __restrict__ rows, const int* __restrict__ cols,
        const float* __restrict__ vals, const int* __restrict__ Cmat,
        const int* __restrict__ bucketBase, int2* __restrict__ pcvp, int nnz) {
    __shared__ int lcnt[NB];                 // hist -> local cursor
    __shared__ int gbase[NB];                // global base - local offset
    __shared__ int sc[256];                  // scan temp
    __shared__ int2 ebuf[PCHUNK];            // 32 KB staging
    __shared__ unsigned short bbuf[PCHUNK];  // 8 KB bucket ids
    int wg = blockIdx.x;
    int c0 = wg * PCHUNK;
    int cend = min(c0 + PCHUNK, nnz);
    int n = cend - c0;

    for (int b = threadIdx.x; b < NB; b += 256) lcnt[b] = 0;
    __syncthreads();
    for (int e = c0 + threadIdx.x; e < cend; e += 256)
        atomicAdd(&lcnt[rows[e] >> BSH], 1);
    __syncthreads();

    // exclusive scan of lcnt[0..NB) with 256-thread chunks + carry
    int carry = 0;
    for (int base = 0; base < NB; base += 256) {
        int b = base + threadIdx.x;
        int v = (b < NB) ? lcnt[b] : 0;
        sc[threadIdx.x] = v;
        __syncthreads();
        for (int off = 1; off < 256; off <<= 1) {
            int t = (threadIdx.x >= (unsigned)off) ? sc[threadIdx.x - off] : 0;
            __syncthreads();
            sc[threadIdx.x] += t;
            __syncthreads();
        }
        if (b < NB) {
            int excl = carry + sc[threadIdx.x] - v;
            gbase[b] = bucketBase[b] + Cmat[(size_t)wg * NB + b] - excl;
            lcnt[b] = excl;   // becomes the local cursor
        }
        carry += sc[255];
        __syncthreads();
    }

    // local bucket-sort into LDS
    for (int e = c0 + threadIdx.x; e < cend; e += 256) {
        int r = rows[e];
        int b = r >> BSH;
        int lpos = atomicAdd(&lcnt[b], 1);
        ebuf[lpos] = make_int2(((r & (BROWS - 1)) << 18) | cols[e], __float_as_int(vals[e]));
        bbuf[lpos] = (unsigned short)b;
    }
    __syncthreads();

    // stream out: consecutive t -> consecutive global positions within runs
    for (int t = threadIdx.x; t < n; t += 256) {
        int b = bbuf[t];
        pcvp[gbase[b] + t] = ebuf[t];
    }
}

// ---------------------------------------------------------------------------
// bsort (round-18 proven version): one WG per 128-row bucket; LDS hist +
// scan -> rowptr; sort (col,val) into LDS staging at exact local positions,
// then stream out coalesced. cv.x stores col<<6 (pre-shifted element addr).
// Fallback direct path if bucket overflows staging (never at 8σ).
// ---------------------------------------------------------------------------
__global__ __launch_bounds__(256) void lgcn_bsort(const int2* __restrict__ pcvp,
                                                  const int* __restrict__ bucketBase,
                                                  int* __restrict__ rowptr,
                                                  int2* __restrict__ cv) {
    __shared__ int sm[BROWS];
    __shared__ int cur[BROWS];
    __shared__ int2 sbuf[CAPB];              // 36 KB staging
    int b = blockIdx.x;
    int beg = bucketBase[b];
    int end = bucketBase[b + 1];
    int n = end - beg;

    if (threadIdx.x < BROWS) sm[threadIdx.x] = 0;
    __syncthreads();
    for (int i = beg + threadIdx.x; i < end; i += 256)
        atomicAdd(&sm[((unsigned)pcvp[i].x) >> 18], 1);
    __syncthreads();

    int c = (threadIdx.x < BROWS) ? sm[threadIdx.x] : 0;
    for (int off = 1; off < BROWS; off <<= 1) {
        int t = (threadIdx.x < BROWS && threadIdx.x >= (unsigned)off)
                    ? sm[threadIdx.x - off] : 0;
        __syncthreads();
        if (threadIdx.x < BROWS) sm[threadIdx.x] += t;
        __syncthreads();
    }
    if (threadIdx.x < BROWS) {
        int excl = sm[threadIdx.x] - c;
        cur[threadIdx.x] = excl;
        int node = b * BROWS + (int)threadIdx.x;
        if (node < N_NODES) rowptr[node] = beg + excl;
    }
    __syncthreads();

    if (n <= CAPB) {
        // staged: sort into LDS, stream out coalesced
        for (int i = beg + threadIdx.x; i < end; i += 256) {
            int2 p = pcvp[i];
            int rl = ((unsigned)p.x) >> 18;
            int lpos = atomicAdd(&cur[rl], 1);
            sbuf[lpos] = make_int2((p.x & COLMASK) << 6, p.y);
        }
        __syncthreads();
        for (int t = threadIdx.x; t < n; t += 256)
            cv[beg + t] = sbuf[t];
    } else {
        // fallback: direct exact-position writes (memory-safe path)
        for (int i = beg + threadIdx.x; i < end; i += 256) {
            int2 p = pcvp[i];
            int rl = ((unsigned)p.x) >> 18;
            int pos = atomicAdd(&cur[rl], 1);
            cv[beg + pos] = make_int2((p.x & COLMASK) << 6, p.y);
        }
    }
}

// ---------------------------------------------------------------------------
// CSR SpMM oct: one wave per row; 8 edges per wave-instruction.
// Lane l: grp=l>>3 (edge slot 0..7), sub=l&7 (dims sub*8..sub*8+7).
// Gather = uint4 (16 B/lane = coalescing sweet spot; 1 KB per instruction).
// Depth-2 ping-pong; unpredicated bulk while e+16 <= end; one predicated
// iteration + epilogue handle the tail. cv.x holds col<<6 (pre-shifted).
// shfl_xor(8,16,32) row reduce; lanes 0-7 do the epilogue (16 B ego or
// 32 B acc). FINAL=true: acc = (e0+e1+e2+s)*scale (streams hoisted).
// ---------------------------------------------------------------------------
#define CONS8(vv, qq)                                                 \
    s0.x = fmaf(vv, blo(qq.x), s0.x);                                 \
    s0.y = fmaf(vv, bhi(qq.x), s0.y);                                 \
    s0.z = fmaf(vv, blo(qq.y), s0.z);                                 \
    s0.w = fmaf(vv, bhi(qq.y), s0.w);                                 \
    s1.x = fmaf(vv, blo(qq.z), s1.x);                                 \
    s1.y = fmaf(vv, bhi(qq.z), s1.y);                                 \
    s1.z = fmaf(vv, blo(qq.w), s1.z);                                 \
    s1.w = fmaf(vv, bhi(qq.w), s1.w);

#define RED3(f) f += __shfl_xor(f, 8); f += __shfl_xor(f, 16); f += __shfl_xor(f, 32);

template <bool FINAL>
__global__ __launch_bounds__(256) void lgcn_spmm_oct(
        const int* __restrict__ rowptr, const int2* __restrict__ cv,
        const unsigned short* __restrict__ x, unsigned short* __restrict__ ego_out,
        const unsigned short* __restrict__ e0, const unsigned short* __restrict__ e1,
        const unsigned short* __restrict__ e2, float* __restrict__ acc, float scale) {
    int row = blockIdx.x * 4 + (threadIdx.x >> 6);
    row = __builtin_amdgcn_readfirstlane(row);   // wave-uniform
    if (row >= N_NODES) return;
    int lane = threadIdx.x & 63;
    int grp  = lane >> 3;
    int sub  = lane & 7;
    int beg = rowptr[row];
    int end = rowptr[row + 1];

    // hoisted epilogue streams (lanes 0-7 only) — overlap the gather loop
    uint4 h0, h1, h2;
    if (FINAL && grp == 0) {
        size_t o16 = (size_t)row * 8 + sub;   // 16-byte granules per row = 8
        h0 = reinterpret_cast<const uint4*>(e0)[o16];
        h1 = reinterpret_cast<const uint4*>(e1)[o16];
        h2 = reinterpret_cast<const uint4*>(e2)[o16];
    }

    float4 s0 = make_float4(0.f, 0.f, 0.f, 0.f);
    float4 s1 = make_float4(0.f, 0.f, 0.f, 0.f);
    if (beg < end) {
        int lim = end - 1;
        int so = sub << 3;   // element offset within row
        // clamped prologue: A@beg, B@beg+8
        int   iA = min(beg + grp, lim);
        int2  pA = cv[iA];
        float vA = (beg + grp <= lim) ? __int_as_float(pA.y) : 0.f;
        uint4 qA = *reinterpret_cast<const uint4*>(x + (unsigned)pA.x + so);
        int   iB = min(beg + 8 + grp, lim);
        int2  pB = cv[iB];
        float vB = (beg + 8 + grp <= lim) ? __int_as_float(pB.y) : 0.f;
        uint4 qB = *reinterpret_cast<const uint4*>(x + (unsigned)pB.x + so);

        int e = beg + 16;
        // unpredicated bulk: all refill indices < end
        for (; e + 16 <= end; e += 16) {
            CONS8(vA, qA)
            pA = cv[e + grp];
            vA = __int_as_float(pA.y);
            qA = *reinterpret_cast<const uint4*>(x + (unsigned)pA.x + so);
            CONS8(vB, qB)
            pB = cv[e + 8 + grp];
            vB = __int_as_float(pB.y);
            qB = *reinterpret_cast<const uint4*>(x + (unsigned)pB.x + so);
        }
        // one predicated (clamped) iteration for the tail
        if (e < end) {
            CONS8(vA, qA)
            iA = min(e + grp, lim);
            pA = cv[iA];
            vA = (e + grp <= lim) ? __int_as_float(pA.y) : 0.f;
            qA = *reinterpret_cast<const uint4*>(x + (unsigned)pA.x + so);
            CONS8(vB, qB)
            iB = min(e + 8 + grp, lim);
            pB = cv[iB];
            vB = (e + 8 + grp <= lim) ? __int_as_float(pB.y) : 0.f;
            qB = *reinterpret_cast<const uint4*>(x + (unsigned)pB.x + so);
        }
        CONS8(vA, qA)
        CONS8(vB, qB)
    }

    // combine the 8 edge-groups: lanes with same sub
    RED3(s0.x) RED3(s0.y) RED3(s0.z) RED3(s0.w)
    RED3(s1.x) RED3(s1.y) RED3(s1.z) RED3(s1.w)

    if (grp == 0) {
        size_t o16 = (size_t)row * 8 + sub;
        if (!FINAL) {
            uint4 h;
            h.x = (unsigned)f2bf(s0.x) | ((unsigned)f2bf(s0.y) << 16);
            h.y = (unsigned)f2bf(s0.z) | ((unsigned)f2bf(s0.w) << 16);
            h.z = (unsigned)f2bf(s1.x) | ((unsigned)f2bf(s1.y) << 16);
            h.w = (unsigned)f2bf(s1.z) | ((unsigned)f2bf(s1.w) << 16);
            reinterpret_cast<uint4*>(ego_out)[o16] = h;
        } else {
            float4 r0, r1;
            r0.x = (blo(h0.x) + blo(h1.x) + blo(h2.x) + s0.x) * scale;
            r0.y = (bhi(h0.x) + bhi(h1.x) + bhi(h2.x) + s0.y) * scale;
            r0.z = (blo(h0.y) + blo(h1.y) + blo(h2.y) + s0.z) * scale;
            r0.w = (bhi(h0.y) + bhi(h1.y) + bhi(h2.y) + s0.w) * scale;
            r1.x = (blo(h0.z) + blo(h1.z) + blo(h2.z) + s1.x) * scale;
            r1.y = (bhi(h0.z) + bhi(h1.z) + bhi(h2.z) + s1.y) * scale;
            r1.z = (blo(h0.w) + blo(h1.w) + blo(h2.w) + s1.z) * scale;
            r1.w = (bhi(h0.w) + bhi(h1.w) + bhi(h2.w) + s1.w) * scale;
            size_t a4 = (size_t)row * 16 + sub * 2;
            reinterpret_cast<float4*>(acc)[a4]     = r0;
            reinterpret_cast<float4*>(acc)[a4 + 1] = r1;
        }
    }
}

extern "C" void kernel_launch(void* const* d_in, const int* in_sizes, int n_in,
                              void* d_out, int out_size, void* d_ws, size_t ws_size,
                              hipStream_t stream) {
    const int*   rows = (const int*)d_in[0];
    const int*   cols = (const int*)d_in[1];
    const float* vals = (const float*)d_in[2];
    const float* u    = (const float*)d_in[3];
    const float* it   = (const float*)d_in[4];
    const float* up   = (const float*)d_in[5];
    const float* ip   = (const float*)d_in[6];
    const int nnz = in_sizes[0];
    const int nwg = (nnz + PCHUNK - 1) / PCHUNK;

    float* acc = (float*)d_out;

    // workspace layout (~141 MB)
    unsigned short* egoh0 = (unsigned short*)d_ws;                    // 19.2 MB
    unsigned short* egoh1 = egoh0 + (size_t)N_NODES * EMBED;          // 19.2 MB
    unsigned short* egoh2 = egoh1 + (size_t)N_NODES * EMBED;          // 19.2 MB
    int2*  cv         = (int2*)(egoh2 + (size_t)N_NODES * EMBED);     // nnz*8 = 38.4 MB
    int2*  pcvp       = cv + nnz;                                     // nnz*8 = 38.4 MB
    int*   Cmat       = (int*)(pcvp + nnz);                           // nwg*NB ints (~5.5 MB)
    int*   colTotal   = Cmat + (size_t)nwg * NB;                      // NB
    int*   bucketBase = colTotal + NB;                                // NB+1
    int*   rowptr     = bucketBase + NB + 1;                          // N_NODES+1

    const int tpb = 256;
    const int totalVec = N_NODES * EMBED / 4;

    lgcn_init<<<(totalVec + tpb - 1) / tpb, tpb, 0, stream>>>(u, it, up, ip, egoh0);
    lgcn_cnt<<<nwg, tpb, 0, stream>>>(rows, Cmat, nnz);
    lgcn_colscan<<<NB, 256, 0, stream>>>(Cmat, colTotal, nwg);
    lgcn_btscan<<<1, 1024, 0, stream>>>(colTotal, bucketBase, rowptr, nnz);
    lgcn_scatter<<<nwg, tpb, 0, stream>>>(rows, cols, vals, Cmat, bucketBase, pcvp, nnz);
    lgcn_bsort<<<NB, 256, 0, stream>>>(pcvp, bucketBase, rowptr, cv);

    const int spmmBlocks = (N_NODES + 3) / 4;  // 4 rows (waves) per block

    lgcn_spmm_oct<false><<<spmmBlocks, tpb, 0, stream>>>(
        rowptr, cv, egoh0, egoh1, nullptr, nullptr, nullptr, nullptr, 1.0f);
    lgcn_spmm_oct<false><<<spmmBlocks, tpb, 0, stream>>>(
        rowptr, cv, egoh1, egoh2, nullptr, nullptr, nullptr, nullptr, 1.0f);
    lgcn_spmm_oct<true><<<spmmBlocks, tpb, 0, stream>>>(
        rowptr, cv, egoh2, nullptr, egoh0, egoh1, egoh2, acc, 1.0f / (N_LAYERS + 1));
}